// Round 3
// baseline (1999.170 us; speedup 1.0000x reference)
//
#include <hip/hip_runtime.h>
#include <cstddef>

#define HEADS 4
#define HC 128          // HEADS * C
#define SLOPE 0.2f
#define NPB 120         // dst nodes per bucket (LDS acc = 120*128*4 = 61440 B)

__device__ __forceinline__ unsigned short f2bf(float f) {
    unsigned u = __float_as_uint(f);
    u += 0x7fffu + ((u >> 16) & 1u);          // RNE
    return (unsigned short)(u >> 16);
}
__device__ __forceinline__ float bf2f(unsigned short b) {
    return __uint_as_float(((unsigned)b) << 16);
}
__device__ __forceinline__ float edge_w(float v) {
    v = v > 0.f ? v : SLOPE * v;              // leaky relu
    return __expf(v);                         // |logit| small; no max-sub needed
}

// ---------------------------------------------------------------------------
// K1: h2 = bf16(x @ W)   (N x 128) @ (128 x 128), fp32 vector GEMM, bf16 store
// ---------------------------------------------------------------------------
__global__ __launch_bounds__(256)
void gemm_kernel(const float* __restrict__ x, const float* __restrict__ W,
                 unsigned short* __restrict__ h2, int n) {
    __shared__ float Wl[32 * 128];   // [kl][c]
    __shared__ float xT[32 * 132];   // [kl][r], padded stride 132

    const int tid  = threadIdx.x;
    const int row0 = blockIdx.x * 128;
    const int r0   = (tid >> 4) * 8;
    const int c0   = (tid & 15) * 8;

    float acc[8][8];
#pragma unroll
    for (int i = 0; i < 8; ++i)
#pragma unroll
        for (int j = 0; j < 8; ++j) acc[i][j] = 0.f;

    const float4* x4 = (const float4*)x;
    const float4* W4 = (const float4*)W;

    for (int kc = 0; kc < 4; ++kc) {
        for (int i = tid; i < 1024; i += 256)
            ((float4*)Wl)[i] = W4[kc * 1024 + i];
        for (int i = tid; i < 1024; i += 256) {
            int r = i >> 3;
            int q = i & 7;
            int grow = row0 + r;
            float4 v = make_float4(0.f, 0.f, 0.f, 0.f);
            if (grow < n) v = x4[(size_t)grow * 32 + kc * 8 + q];
            int kl = q * 4;
            xT[(kl + 0) * 132 + r] = v.x;
            xT[(kl + 1) * 132 + r] = v.y;
            xT[(kl + 2) * 132 + r] = v.z;
            xT[(kl + 3) * 132 + r] = v.w;
        }
        __syncthreads();
#pragma unroll
        for (int kl = 0; kl < 32; ++kl) {
            float4 xa = *(const float4*)&xT[kl * 132 + r0];
            float4 xb = *(const float4*)&xT[kl * 132 + r0 + 4];
            float4 wa = *(const float4*)&Wl[kl * 128 + c0];
            float4 wb = *(const float4*)&Wl[kl * 128 + c0 + 4];
            float xr[8] = {xa.x, xa.y, xa.z, xa.w, xb.x, xb.y, xb.z, xb.w};
            float wc[8] = {wa.x, wa.y, wa.z, wa.w, wb.x, wb.y, wb.z, wb.w};
#pragma unroll
            for (int i = 0; i < 8; ++i)
#pragma unroll
                for (int j = 0; j < 8; ++j)
                    acc[i][j] = fmaf(xr[i], wc[j], acc[i][j]);
        }
        __syncthreads();
    }

#pragma unroll
    for (int i = 0; i < 8; ++i) {
        int grow = row0 + r0 + i;
        if (grow < n) {
            unsigned p0 = f2bf(acc[i][0]) | ((unsigned)f2bf(acc[i][1]) << 16);
            unsigned p1 = f2bf(acc[i][2]) | ((unsigned)f2bf(acc[i][3]) << 16);
            unsigned p2 = f2bf(acc[i][4]) | ((unsigned)f2bf(acc[i][5]) << 16);
            unsigned p3 = f2bf(acc[i][6]) | ((unsigned)f2bf(acc[i][7]) << 16);
            uint4 pk; pk.x = p0; pk.y = p1; pk.z = p2; pk.w = p3;
            *(uint4*)&h2[(size_t)grow * HC + c0] = pk;
        }
    }
}

// ---------------------------------------------------------------------------
// K2: per-node attention logit halves from bf16 h
// ---------------------------------------------------------------------------
__global__ void att_kernel(const unsigned short* __restrict__ h2,
                           const float* __restrict__ att_src,
                           const float* __restrict__ att_dst,
                           float* __restrict__ a_s, float* __restrict__ a_d, int n) {
    int node = blockIdx.x * blockDim.x + threadIdx.x;
    if (node >= n) return;
    const uint4*  hv = (const uint4*)(h2 + (size_t)node * HC);
    const float4* s4 = (const float4*)att_src;
    const float4* d4 = (const float4*)att_dst;
    float rs[4], rd[4];
#pragma unroll
    for (int hd = 0; hd < 4; ++hd) {
        float ss = 0.f, dd = 0.f;
#pragma unroll
        for (int q = 0; q < 4; ++q) {       // 4 x uint4 = 32 bf16 per head
            uint4 u = hv[hd * 4 + q];
            float f[8];
            f[0] = __uint_as_float(u.x << 16); f[1] = __uint_as_float(u.x & 0xffff0000u);
            f[2] = __uint_as_float(u.y << 16); f[3] = __uint_as_float(u.y & 0xffff0000u);
            f[4] = __uint_as_float(u.z << 16); f[5] = __uint_as_float(u.z & 0xffff0000u);
            f[6] = __uint_as_float(u.w << 16); f[7] = __uint_as_float(u.w & 0xffff0000u);
            float4 a1 = s4[hd * 8 + q * 2],  a1b = s4[hd * 8 + q * 2 + 1];
            float4 a2 = d4[hd * 8 + q * 2],  a2b = d4[hd * 8 + q * 2 + 1];
            ss += f[0]*a1.x + f[1]*a1.y + f[2]*a1.z + f[3]*a1.w
                + f[4]*a1b.x + f[5]*a1b.y + f[6]*a1b.z + f[7]*a1b.w;
            dd += f[0]*a2.x + f[1]*a2.y + f[2]*a2.z + f[3]*a2.w
                + f[4]*a2b.x + f[5]*a2b.y + f[6]*a2b.z + f[7]*a2b.w;
        }
        rs[hd] = ss; rd[hd] = dd;
    }
    ((float4*)a_s)[node] = make_float4(rs[0], rs[1], rs[2], rs[3]);
    ((float4*)a_d)[node] = make_float4(rd[0], rd[1], rd[2], rd[3]);
}

// ---------------------------------------------------------------------------
// Bucket pipeline: hist -> scan -> binned scatter (coarse sort only)
// ---------------------------------------------------------------------------
__global__ void zerob_kernel(int* __restrict__ bcount, int nbuck) {
    int i = blockIdx.x * blockDim.x + threadIdx.x;
    if (i < nbuck) bcount[i] = 0;
}

__global__ __launch_bounds__(256)
void hist_kernel(const int* __restrict__ ei, int E, int n, int nbuck,
                 int* __restrict__ bcount) {
    __shared__ int lh[1024];
    int tid = threadIdx.x;
    for (int i = tid; i < nbuck; i += 256) lh[i] = 0;
    __syncthreads();
    int Etot = E + n;
    int stride = gridDim.x * 256;
    for (int e = blockIdx.x * 256 + tid; e < Etot; e += stride) {
        int dst = (e < E) ? ei[E + e] : (e - E);
        atomicAdd(&lh[dst / NPB], 1);
    }
    __syncthreads();
    for (int i = tid; i < nbuck; i += 256)
        if (lh[i]) atomicAdd(&bcount[i], lh[i]);
}

__global__ __launch_bounds__(1024)
void scan_kernel(const int* __restrict__ bcount, int* __restrict__ bstart,
                 int* __restrict__ bcursor, int nbuck) {
    __shared__ int tmp[1024];
    int t = threadIdx.x;
    int d = (t < nbuck) ? bcount[t] : 0;
    tmp[t] = d;
    __syncthreads();
#pragma unroll
    for (int off = 1; off < 1024; off <<= 1) {
        int v = (t >= off) ? tmp[t - off] : 0;
        __syncthreads();
        tmp[t] += v;
        __syncthreads();
    }
    if (t < nbuck) { bstart[t] = tmp[t] - d; bcursor[t] = tmp[t] - d; }
}

__global__ void scatter_kernel(const int* __restrict__ ei, int E, int n,
                               int* __restrict__ bcursor, int2* __restrict__ binned) {
    int e = blockIdx.x * blockDim.x + threadIdx.x;
    if (e >= E + n) return;
    int src, dst;
    if (e < E) { src = ei[e]; dst = ei[E + e]; }
    else       { src = e - E; dst = src; }
    int pos = atomicAdd(&bcursor[dst / NPB], 1);
    int2 ed; ed.x = src; ed.y = dst;
    binned[pos] = ed;
}

// ---------------------------------------------------------------------------
// K5: bucket aggregation. One block per bucket of NPB dst nodes; LDS f32
// accumulators; out = (sum w*h)/(sum w) + bias, written once, atomic-free
// in global memory.
// ---------------------------------------------------------------------------
__global__ __launch_bounds__(512)
void bucket_agg_kernel(const int* __restrict__ bstart, const int* __restrict__ bend,
                       const int2* __restrict__ binned,
                       const float* __restrict__ a_s, const float* __restrict__ a_d,
                       const unsigned short* __restrict__ h2,
                       const float* __restrict__ bias,
                       float* __restrict__ out, int n) {
    __shared__ float acc[NPB * HC];        // 61440 B
    __shared__ float wsum[NPB * HEADS];    // 1920 B
    int b = blockIdx.x;
    int dst0 = b * NPB;
    int rows = n - dst0; if (rows > NPB) rows = NPB;
    int tid = threadIdx.x;

    for (int i = tid; i < NPB * HC; i += 512) acc[i] = 0.f;
    for (int i = tid; i < NPB * HEADS; i += 512) wsum[i] = 0.f;
    __syncthreads();

    int start = bstart[b], end = bend[b];
    int lane = tid & 127;
    int slot = tid >> 7;          // 4 edge slots
    int head = lane >> 5;

    for (int e = start + slot; e < end; e += 16) {     // unroll 4 per slot
        int2 ed[4]; bool v[4]; float w[4], hv[4];
#pragma unroll
        for (int k = 0; k < 4; ++k) {
            int ee = e + 4 * k;
            v[k] = ee < end;
            if (v[k]) ed[k] = binned[ee];
        }
#pragma unroll
        for (int k = 0; k < 4; ++k) {
            if (v[k]) {
                float logit = a_s[(size_t)ed[k].x * 4 + head]
                            + a_d[(size_t)ed[k].y * 4 + head];
                w[k]  = edge_w(logit);
                hv[k] = bf2f(h2[(size_t)ed[k].x * HC + lane]);
            }
        }
#pragma unroll
        for (int k = 0; k < 4; ++k) {
            if (v[k]) {
                atomicAdd(&acc[(ed[k].y - dst0) * HC + lane], w[k] * hv[k]);
                if ((lane & 31) == 0)
                    atomicAdd(&wsum[(ed[k].y - dst0) * 4 + head], w[k]);
            }
        }
    }
    __syncthreads();

    for (int i = tid; i < rows * HC; i += 512) {
        int r = i >> 7, c = i & 127;
        out[(size_t)(dst0 + r) * HC + c] = acc[i] / wsum[r * 4 + (c >> 5)] + bias[c];
    }
}

// ---------------------------------------------------------------------------
extern "C" void kernel_launch(void* const* d_in, const int* in_sizes, int n_in,
                              void* d_out, int out_size, void* d_ws, size_t ws_size,
                              hipStream_t stream) {
    const float* x       = (const float*)d_in[0];
    const int*   ei      = (const int*)d_in[1];
    const float* W       = (const float*)d_in[2];
    const float* att_src = (const float*)d_in[3];
    const float* att_dst = (const float*)d_in[4];
    const float* bias    = (const float*)d_in[5];

    int n = in_sizes[0] / HC;        // 100000
    int E = in_sizes[1] / 2;         // 1600000
    int Etot = E + n;
    int nbuck = (n + NPB - 1) / NPB; // 834 (<=1024 for scan)

    // workspace: h2[n*128 bf16] | a_s[n*4 f] | a_d[n*4 f] |
    //            bcount[1024 i] | bstart[1024 i] | bcursor[1024 i] | binned[Etot int2]
    unsigned short* h2   = (unsigned short*)d_ws;
    float* a_s    = (float*)(h2 + (size_t)n * HC);
    float* a_d    = a_s + (size_t)n * HEADS;
    int*   bcount = (int*)(a_d + (size_t)n * HEADS);
    int*   bstart = bcount + 1024;
    int*   bcursor= bstart + 1024;
    int2*  binned = (int2*)(bcursor + 1024);
    float* out    = (float*)d_out;

    gemm_kernel<<<(n + 127) / 128, 256, 0, stream>>>(x, W, h2, n);
    att_kernel<<<(n + 255) / 256, 256, 0, stream>>>(h2, att_src, att_dst, a_s, a_d, n);

    zerob_kernel<<<(nbuck + 255) / 256, 256, 0, stream>>>(bcount, nbuck);
    hist_kernel<<<512, 256, 0, stream>>>(ei, E, n, nbuck, bcount);
    scan_kernel<<<1, 1024, 0, stream>>>(bcount, bstart, bcursor, nbuck);
    scatter_kernel<<<(Etot + 255) / 256, 256, 0, stream>>>(ei, E, n, bcursor, binned);
    // after scatter, bcursor[b] == end of bucket b
    bucket_agg_kernel<<<nbuck, 512, 0, stream>>>(bstart, bcursor, binned,
                                                 a_s, a_d, h2, bias, out, n);
}

// Round 4
// 728.124 us; speedup vs baseline: 2.7456x; 2.7456x over previous
//
#include <hip/hip_runtime.h>
#include <cstddef>

#define HEADS 4
#define HC 128          // HEADS * C
#define SLOPE 0.2f
#define NPB 120         // dst nodes per refine bucket

using half8 = __attribute__((ext_vector_type(8))) _Float16;
using f32x4 = __attribute__((ext_vector_type(4))) float;

__device__ __forceinline__ float edge_w(float v) {
    v = v > 0.f ? v : SLOPE * v;              // leaky relu
    return __expf(v);                         // |logit| small; no max-sub needed
}
__device__ __forceinline__ float2 up2(unsigned w) {   // unpack 2 fp16
    union { unsigned u; _Float16 f[2]; } c; c.u = w;
    return make_float2((float)c.f[0], (float)c.f[1]);
}

// ---------------------------------------------------------------------------
// K0: WTh[n][k] = fp16(W[k][n])  (transpose + cast, 128x128)
// ---------------------------------------------------------------------------
__global__ void wt_kernel(const float* __restrict__ W, _Float16* __restrict__ WTh) {
    int k = threadIdx.x;          // 0..127
    int nn = blockIdx.x;          // 0..127
    WTh[nn * HC + k] = (_Float16)W[k * HC + nn];
}

// ---------------------------------------------------------------------------
// K1: h2 = fp16(x @ W) via MFMA 16x16x32 f16.
// Block = 256 thr = 4 waves; wave w owns rows r0=blk*64+w*16, all 128 cols
// (8 col-tiles). A-frag: A[m=lane&15][k=quad*8+j]; B-frag from WTh (row = out
// col, 8 contiguous fp16); C/D: col=lane&15, row=quad*4+reg.
// ---------------------------------------------------------------------------
__global__ __launch_bounds__(256)
void gemm_mfma_kernel(const float* __restrict__ x, const _Float16* __restrict__ WTh,
                      _Float16* __restrict__ h2, int n) {
    int tid  = threadIdx.x;
    int wv   = tid >> 6;
    int lane = tid & 63;
    int t    = lane & 15;     // A row / D col within tile
    int q    = lane >> 4;     // quad
    int r0   = blockIdx.x * 64 + wv * 16;

    f32x4 acc[8];
#pragma unroll
    for (int ct = 0; ct < 8; ++ct) acc[ct] = (f32x4){0.f, 0.f, 0.f, 0.f};

    int  arow = r0 + t;
    bool aval = arow < n;
    const float* xp = x + (size_t)(aval ? arow : 0) * HC;

    for (int kc = 0; kc < 4; ++kc) {
        int k0 = kc * 32 + q * 8;
        half8 a;
        float4 fa = *(const float4*)(xp + k0);
        float4 fb = *(const float4*)(xp + k0 + 4);
        if (!aval) { fa = make_float4(0.f,0.f,0.f,0.f); fb = fa; }
        a[0] = (_Float16)fa.x; a[1] = (_Float16)fa.y;
        a[2] = (_Float16)fa.z; a[3] = (_Float16)fa.w;
        a[4] = (_Float16)fb.x; a[5] = (_Float16)fb.y;
        a[6] = (_Float16)fb.z; a[7] = (_Float16)fb.w;
#pragma unroll
        for (int ct = 0; ct < 8; ++ct) {
            half8 b = *(const half8*)(WTh + (size_t)(ct * 16 + t) * HC + k0);
            acc[ct] = __builtin_amdgcn_mfma_f32_16x16x32_f16(a, b, acc[ct], 0, 0, 0);
        }
    }

#pragma unroll
    for (int reg = 0; reg < 4; ++reg) {
        int row = r0 + q * 4 + reg;
        if (row < n) {
#pragma unroll
            for (int ct = 0; ct < 8; ++ct)
                h2[(size_t)row * HC + ct * 16 + t] = (_Float16)acc[ct][reg];
        }
    }
}

// ---------------------------------------------------------------------------
// K2: per-node attention logit halves from fp16 h
// ---------------------------------------------------------------------------
__global__ void att_kernel(const _Float16* __restrict__ h2,
                           const float* __restrict__ att_src,
                           const float* __restrict__ att_dst,
                           float* __restrict__ a_s, float* __restrict__ a_d, int n) {
    int node = blockIdx.x * blockDim.x + threadIdx.x;
    if (node >= n) return;
    const half8*  hv = (const half8*)(h2 + (size_t)node * HC);
    const float4* s4 = (const float4*)att_src;
    const float4* d4 = (const float4*)att_dst;
    float rs[4], rd[4];
#pragma unroll
    for (int hd = 0; hd < 4; ++hd) {
        float ss = 0.f, dd = 0.f;
#pragma unroll
        for (int qq = 0; qq < 4; ++qq) {
            half8 hq = hv[hd * 4 + qq];
            float4 a1 = s4[hd * 8 + qq * 2], a1b = s4[hd * 8 + qq * 2 + 1];
            float4 a2 = d4[hd * 8 + qq * 2], a2b = d4[hd * 8 + qq * 2 + 1];
            float f0 = (float)hq[0], f1 = (float)hq[1], f2 = (float)hq[2], f3 = (float)hq[3];
            float f4 = (float)hq[4], f5 = (float)hq[5], f6 = (float)hq[6], f7 = (float)hq[7];
            ss += f0*a1.x + f1*a1.y + f2*a1.z + f3*a1.w
                + f4*a1b.x + f5*a1b.y + f6*a1b.z + f7*a1b.w;
            dd += f0*a2.x + f1*a2.y + f2*a2.z + f3*a2.w
                + f4*a2b.x + f5*a2b.y + f6*a2b.z + f7*a2b.w;
        }
        rs[hd] = ss; rd[hd] = dd;
    }
    ((float4*)a_s)[node] = make_float4(rs[0], rs[1], rs[2], rs[3]);
    ((float4*)a_d)[node] = make_float4(rd[0], rd[1], rd[2], rd[3]);
}

// ---------------------------------------------------------------------------
// CSR build: deg histogram -> 3-stage exclusive scan -> two-level scatter
// ---------------------------------------------------------------------------
__global__ void zero_deg_kernel(int* __restrict__ deg, int n) {
    int i = blockIdx.x * blockDim.x + threadIdx.x;
    if (i < n) deg[i] = 0;
}

__global__ void hist_kernel(const int* __restrict__ ei, int E, int n,
                            int* __restrict__ deg) {
    int e = blockIdx.x * blockDim.x + threadIdx.x;
    if (e >= E + n) return;
    int dst = (e < E) ? ei[E + e] : (e - E);
    atomicAdd(&deg[dst], 1);
}

__global__ __launch_bounds__(1024)
void scan1_kernel(const int* __restrict__ deg, int* __restrict__ rowstart,
                  int* __restrict__ bsum, int n) {
    __shared__ int tmp[1024];
    int t = threadIdx.x;
    int i = blockIdx.x * 1024 + t;
    int d = (i < n) ? deg[i] : 0;
    tmp[t] = d;
    __syncthreads();
#pragma unroll
    for (int off = 1; off < 1024; off <<= 1) {
        int v = (t >= off) ? tmp[t - off] : 0;
        __syncthreads();
        tmp[t] += v;
        __syncthreads();
    }
    if (i < n) rowstart[i] = tmp[t] - d;          // exclusive within chunk
    if (t == 1023) bsum[blockIdx.x] = tmp[t];
}

__global__ __launch_bounds__(128)
void scan2_kernel(int* __restrict__ bsum, int nb) {
    __shared__ int tmp[128];
    int t = threadIdx.x;
    int d = (t < nb) ? bsum[t] : 0;
    tmp[t] = d;
    __syncthreads();
#pragma unroll
    for (int off = 1; off < 128; off <<= 1) {
        int v = (t >= off) ? tmp[t - off] : 0;
        __syncthreads();
        tmp[t] += v;
        __syncthreads();
    }
    if (t < nb) bsum[t] = tmp[t] - d;
}

__global__ void scan3_kernel(int* __restrict__ rowstart,
                             const int* __restrict__ bsum, int n) {
    int i = blockIdx.x * blockDim.x + threadIdx.x;
    if (i < n) rowstart[i] += bsum[i >> 10];
}

__global__ void bcur_kernel(const int* __restrict__ rowstart,
                            int* __restrict__ bcursor, int n, int nbuck) {
    int b = blockIdx.x * blockDim.x + threadIdx.x;
    if (b < nbuck) bcursor[b] = rowstart[b * NPB];
}

// coarse scatter: append (src,dst) into the dst's bucket region (contiguous)
__global__ void scatter_kernel(const int* __restrict__ ei, int E, int n,
                               int* __restrict__ bcursor, int2* __restrict__ binned) {
    int e = blockIdx.x * blockDim.x + threadIdx.x;
    if (e >= E + n) return;
    int src, dst;
    if (e < E) { src = ei[e]; dst = ei[E + e]; }
    else       { src = e - E; dst = src; }
    int pos = atomicAdd(&bcursor[dst / NPB], 1);
    binned[pos] = make_int2(src, dst);
}

// refine: within each bucket, place edges at exact CSR slots (writes stay in
// the bucket's ~8 KB window; LDS cursors, 120 addrs, low contention)
__global__ __launch_bounds__(256)
void refine_kernel(const int* __restrict__ rowstart, const int2* __restrict__ binned,
                   int* __restrict__ sorted, int n, int Etot) {
    __shared__ int cur[NPB];
    int b = blockIdx.x;
    int dst0 = b * NPB;
    int rows = n - dst0; if (rows > NPB) rows = NPB;
    int tid = threadIdx.x;
    for (int i = tid; i < rows; i += 256) cur[i] = rowstart[dst0 + i];
    __syncthreads();
    int bstart = rowstart[dst0];
    int bend   = (dst0 + NPB < n) ? rowstart[dst0 + NPB] : Etot;
    for (int e = bstart + tid; e < bend; e += 256) {
        int2 ed = binned[e];
        int pos = atomicAdd(&cur[ed.y - dst0], 1);
        sorted[pos] = ed.x;
    }
}

// ---------------------------------------------------------------------------
// K5: aggregation. One wave per dst; lane owns 2 channels (one 4-B fp16x2
// load per edge). Register accumulate, single write, atomic-free.
// out[dst,:] = (sum_e w_e * h[src_e,:]) / (sum_e w_e) + bias
// ---------------------------------------------------------------------------
__global__ __launch_bounds__(256)
void agg_kernel(const int* __restrict__ rowstart, const int* __restrict__ deg,
                const int* __restrict__ sorted,
                const float* __restrict__ a_s, const float* __restrict__ a_d,
                const _Float16* __restrict__ h2, const float* __restrict__ bias,
                float* __restrict__ out, int n) {
    int dst = blockIdx.x * 4 + (threadIdx.x >> 6);
    if (dst >= n) return;
    int lane = threadIdx.x & 63;
    int head = lane >> 4;                 // channels 2*lane, 2*lane+1 share head
    int start = rowstart[dst];
    int end   = start + deg[dst];

    float ad = a_d[(size_t)dst * 4 + head];
    const unsigned* h2u = (const unsigned*)h2;
    float accx = 0.f, accy = 0.f, wsum = 0.f;

    int j = start;
    for (; j + 3 < end; j += 4) {
        int s0 = sorted[j], s1 = sorted[j + 1], s2 = sorted[j + 2], s3 = sorted[j + 3];
        float w0 = edge_w(a_s[(size_t)s0 * 4 + head] + ad);
        float w1 = edge_w(a_s[(size_t)s1 * 4 + head] + ad);
        float w2 = edge_w(a_s[(size_t)s2 * 4 + head] + ad);
        float w3 = edge_w(a_s[(size_t)s3 * 4 + head] + ad);
        float2 f0 = up2(h2u[(size_t)s0 * 64 + lane]);
        float2 f1 = up2(h2u[(size_t)s1 * 64 + lane]);
        float2 f2 = up2(h2u[(size_t)s2 * 64 + lane]);
        float2 f3 = up2(h2u[(size_t)s3 * 64 + lane]);
        accx = fmaf(w0, f0.x, accx); accy = fmaf(w0, f0.y, accy);
        accx = fmaf(w1, f1.x, accx); accy = fmaf(w1, f1.y, accy);
        accx = fmaf(w2, f2.x, accx); accy = fmaf(w2, f2.y, accy);
        accx = fmaf(w3, f3.x, accx); accy = fmaf(w3, f3.y, accy);
        wsum += (w0 + w1) + (w2 + w3);
    }
    for (; j < end; ++j) {
        int s0 = sorted[j];
        float w0 = edge_w(a_s[(size_t)s0 * 4 + head] + ad);
        float2 f0 = up2(h2u[(size_t)s0 * 64 + lane]);
        accx = fmaf(w0, f0.x, accx); accy = fmaf(w0, f0.y, accy);
        wsum += w0;
    }

    float inv = 1.f / wsum;               // deg >= 1 (self-loop) => wsum > 0
    float2 b2 = *(const float2*)&bias[lane * 2];
    *(float2*)&out[(size_t)dst * HC + lane * 2] =
        make_float2(accx * inv + b2.x, accy * inv + b2.y);
}

// ---------------------------------------------------------------------------
extern "C" void kernel_launch(void* const* d_in, const int* in_sizes, int n_in,
                              void* d_out, int out_size, void* d_ws, size_t ws_size,
                              hipStream_t stream) {
    const float* x       = (const float*)d_in[0];
    const int*   ei      = (const int*)d_in[1];
    const float* W       = (const float*)d_in[2];
    const float* att_src = (const float*)d_in[3];
    const float* att_dst = (const float*)d_in[4];
    const float* bias    = (const float*)d_in[5];

    int n = in_sizes[0] / HC;        // 100000
    int E = in_sizes[1] / 2;         // 1600000
    int Etot = E + n;
    int nbuck = (n + NPB - 1) / NPB; // 834
    int NB = (n + 1023) / 1024;      // 98 scan chunks

    // workspace: h2[n*128 h] | WTh[128*128 h] | a_s[n*4 f] | a_d[n*4 f] |
    //            deg[n i] | rowstart[n i] | bsum[128 i] | bcursor[1024 i] |
    //            binned[Etot int2] | sorted[Etot i]
    _Float16* h2     = (_Float16*)d_ws;
    _Float16* WTh    = h2 + (size_t)n * HC;
    float* a_s       = (float*)(WTh + HC * HC);
    float* a_d       = a_s + (size_t)n * HEADS;
    int*   deg       = (int*)(a_d + (size_t)n * HEADS);
    int*   rowstart  = deg + n;
    int*   bsum      = rowstart + n;
    int*   bcursor   = bsum + 128;
    int2*  binned    = (int2*)(bcursor + 1024);
    int*   sorted    = (int*)(binned + Etot);
    float* out       = (float*)d_out;

    wt_kernel<<<HC, HC, 0, stream>>>(W, WTh);
    gemm_mfma_kernel<<<(n + 63) / 64, 256, 0, stream>>>(x, WTh, h2, n);
    att_kernel<<<(n + 255) / 256, 256, 0, stream>>>(h2, att_src, att_dst, a_s, a_d, n);

    zero_deg_kernel<<<(n + 255) / 256, 256, 0, stream>>>(deg, n);
    hist_kernel<<<(Etot + 255) / 256, 256, 0, stream>>>(ei, E, n, deg);
    scan1_kernel<<<NB, 1024, 0, stream>>>(deg, rowstart, bsum, n);
    scan2_kernel<<<1, 128, 0, stream>>>(bsum, NB);
    scan3_kernel<<<(n + 255) / 256, 256, 0, stream>>>(rowstart, bsum, n);
    bcur_kernel<<<(nbuck + 255) / 256, 256, 0, stream>>>(rowstart, bcursor, n, nbuck);
    scatter_kernel<<<(Etot + 255) / 256, 256, 0, stream>>>(ei, E, n, bcursor, binned);
    refine_kernel<<<nbuck, 256, 0, stream>>>(rowstart, binned, sorted, n, Etot);

    agg_kernel<<<(n + 3) / 4, 256, 0, stream>>>(rowstart, deg, sorted,
                                                a_s, a_d, h2, bias, out, n);
}

// Round 5
// 348.667 us; speedup vs baseline: 5.7337x; 2.0883x over previous
//
#include <hip/hip_runtime.h>
#include <cstddef>

#define HEADS 4
#define HC 128          // HEADS * C
#define SLOPE 0.2f
#define NSB 256         // super-buckets for the 2-pass partition

using half8 = __attribute__((ext_vector_type(8))) _Float16;
using f32x4 = __attribute__((ext_vector_type(4))) float;

__device__ __forceinline__ float edge_w(float v) {
    v = v > 0.f ? v : SLOPE * v;              // leaky relu
    return __expf(v);                         // |logit| small; no max-sub needed
}
__device__ __forceinline__ float2 up2(unsigned w) {   // unpack 2 fp16
    union { unsigned u; _Float16 f[2]; } c; c.u = w;
    return make_float2((float)c.f[0], (float)c.f[1]);
}

// ---------------------------------------------------------------------------
// K0: WTh[n][k] = fp16(W[k][n])  (transpose + cast, 128x128)
// ---------------------------------------------------------------------------
__global__ void wt_kernel(const float* __restrict__ W, _Float16* __restrict__ WTh) {
    int k = threadIdx.x;          // 0..127
    int nn = blockIdx.x;          // 0..127
    WTh[nn * HC + k] = (_Float16)W[k * HC + nn];
}

// ---------------------------------------------------------------------------
// K1: h2 = fp16(x @ W) via MFMA 16x16x32 f16 (layouts per cdna4 guide §3)
// ---------------------------------------------------------------------------
__global__ __launch_bounds__(256)
void gemm_mfma_kernel(const float* __restrict__ x, const _Float16* __restrict__ WTh,
                      _Float16* __restrict__ h2, int n) {
    int tid  = threadIdx.x;
    int wv   = tid >> 6;
    int lane = tid & 63;
    int t    = lane & 15;     // A row / D col within tile
    int q    = lane >> 4;     // quad
    int r0   = blockIdx.x * 64 + wv * 16;

    f32x4 acc[8];
#pragma unroll
    for (int ct = 0; ct < 8; ++ct) acc[ct] = (f32x4){0.f, 0.f, 0.f, 0.f};

    int  arow = r0 + t;
    bool aval = arow < n;
    const float* xp = x + (size_t)(aval ? arow : 0) * HC;

    for (int kc = 0; kc < 4; ++kc) {
        int k0 = kc * 32 + q * 8;
        half8 a;
        float4 fa = *(const float4*)(xp + k0);
        float4 fb = *(const float4*)(xp + k0 + 4);
        if (!aval) { fa = make_float4(0.f,0.f,0.f,0.f); fb = fa; }
        a[0] = (_Float16)fa.x; a[1] = (_Float16)fa.y;
        a[2] = (_Float16)fa.z; a[3] = (_Float16)fa.w;
        a[4] = (_Float16)fb.x; a[5] = (_Float16)fb.y;
        a[6] = (_Float16)fb.z; a[7] = (_Float16)fb.w;
#pragma unroll
        for (int ct = 0; ct < 8; ++ct) {
            half8 b = *(const half8*)(WTh + (size_t)(ct * 16 + t) * HC + k0);
            acc[ct] = __builtin_amdgcn_mfma_f32_16x16x32_f16(a, b, acc[ct], 0, 0, 0);
        }
    }

#pragma unroll
    for (int reg = 0; reg < 4; ++reg) {
        int row = r0 + q * 4 + reg;
        if (row < n) {
#pragma unroll
            for (int ct = 0; ct < 8; ++ct)
                h2[(size_t)row * HC + ct * 16 + t] = (_Float16)acc[ct][reg];
        }
    }
}

// ---------------------------------------------------------------------------
// K2: per-node attention logit halves from fp16 h
// ---------------------------------------------------------------------------
__global__ void att_kernel(const _Float16* __restrict__ h2,
                           const float* __restrict__ att_src,
                           const float* __restrict__ att_dst,
                           float* __restrict__ a_s, float* __restrict__ a_d, int n) {
    int node = blockIdx.x * blockDim.x + threadIdx.x;
    if (node >= n) return;
    const half8*  hv = (const half8*)(h2 + (size_t)node * HC);
    const float4* s4 = (const float4*)att_src;
    const float4* d4 = (const float4*)att_dst;
    float rs[4], rd[4];
#pragma unroll
    for (int hd = 0; hd < 4; ++hd) {
        float ss = 0.f, dd = 0.f;
#pragma unroll
        for (int qq = 0; qq < 4; ++qq) {
            half8 hq = hv[hd * 4 + qq];
            float4 a1 = s4[hd * 8 + qq * 2], a1b = s4[hd * 8 + qq * 2 + 1];
            float4 a2 = d4[hd * 8 + qq * 2], a2b = d4[hd * 8 + qq * 2 + 1];
            float f0 = (float)hq[0], f1 = (float)hq[1], f2 = (float)hq[2], f3 = (float)hq[3];
            float f4 = (float)hq[4], f5 = (float)hq[5], f6 = (float)hq[6], f7 = (float)hq[7];
            ss += f0*a1.x + f1*a1.y + f2*a1.z + f3*a1.w
                + f4*a1b.x + f5*a1b.y + f6*a1b.z + f7*a1b.w;
            dd += f0*a2.x + f1*a2.y + f2*a2.z + f3*a2.w
                + f4*a2b.x + f5*a2b.y + f6*a2b.z + f7*a2b.w;
        }
        rs[hd] = ss; rd[hd] = dd;
    }
    ((float4*)a_s)[node] = make_float4(rs[0], rs[1], rs[2], rs[3]);
    ((float4*)a_d)[node] = make_float4(rd[0], rd[1], rd[2], rd[3]);
}

// ---------------------------------------------------------------------------
// CSR build: deg histogram -> 3-stage exclusive scan
// ---------------------------------------------------------------------------
__global__ void zero_deg_kernel(int* __restrict__ deg, int n) {
    int i = blockIdx.x * blockDim.x + threadIdx.x;
    if (i < n) deg[i] = 0;
}

__global__ void hist_kernel(const int* __restrict__ ei, int E, int n,
                            int* __restrict__ deg) {
    int e = blockIdx.x * blockDim.x + threadIdx.x;
    if (e >= E + n) return;
    int dst = (e < E) ? ei[E + e] : (e - E);
    atomicAdd(&deg[dst], 1);
}

__global__ __launch_bounds__(1024)
void scan1_kernel(const int* __restrict__ deg, int* __restrict__ rowstart,
                  int* __restrict__ bsum, int n) {
    __shared__ int tmp[1024];
    int t = threadIdx.x;
    int i = blockIdx.x * 1024 + t;
    int d = (i < n) ? deg[i] : 0;
    tmp[t] = d;
    __syncthreads();
#pragma unroll
    for (int off = 1; off < 1024; off <<= 1) {
        int v = (t >= off) ? tmp[t - off] : 0;
        __syncthreads();
        tmp[t] += v;
        __syncthreads();
    }
    if (i < n) rowstart[i] = tmp[t] - d;          // exclusive within chunk
    if (t == 1023) bsum[blockIdx.x] = tmp[t];
}

__global__ __launch_bounds__(128)
void scan2_kernel(int* __restrict__ bsum, int nb) {
    __shared__ int tmp[128];
    int t = threadIdx.x;
    int d = (t < nb) ? bsum[t] : 0;
    tmp[t] = d;
    __syncthreads();
#pragma unroll
    for (int off = 1; off < 128; off <<= 1) {
        int v = (t >= off) ? tmp[t - off] : 0;
        __syncthreads();
        tmp[t] += v;
        __syncthreads();
    }
    if (t < nb) bsum[t] = tmp[t] - d;
}

__global__ void scan3_kernel(int* __restrict__ rowstart,
                             const int* __restrict__ bsum, int n) {
    int i = blockIdx.x * blockDim.x + threadIdx.x;
    if (i < n) rowstart[i] += bsum[i >> 10];
}

// ---------------------------------------------------------------------------
// Two-pass partition with block-private line ownership (no cross-XCD false
// sharing on append lines).
// ---------------------------------------------------------------------------
__global__ void sbinit_kernel(const int* __restrict__ rowstart,
                              int* __restrict__ sbcursor, int n, int sbn) {
    int b = threadIdx.x;          // 1 block of NSB threads
    int node = b * sbn;
    if (node >= n) node = n - 1;  // (unreachable for our sizes; safety)
    sbcursor[b] = rowstart[node];
}

// Pass A: each block owns a 4096-edge chunk; one global atomic per
// block x super-bucket reserves a private run; int2(src,dst) written into
// block-owned runs (<=2 blocks per 64-B line).
__global__ __launch_bounds__(256)
void partition_kernel(const int* __restrict__ ei, int E, int n, int sbn,
                      int* __restrict__ sbcursor, int2* __restrict__ binned) {
    __shared__ int cnt[NSB];
    __shared__ int gbase[NSB];
    int tid = threadIdx.x;
    int Etot = E + n;
    int e0 = blockIdx.x * 4096;
    int eend = e0 + 4096; if (eend > Etot) eend = Etot;

    cnt[tid] = 0;
    __syncthreads();
    for (int e = e0 + tid; e < eend; e += 256) {
        int dst = (e < E) ? ei[E + e] : (e - E);
        atomicAdd(&cnt[dst / sbn], 1);
    }
    __syncthreads();
    gbase[tid] = atomicAdd(&sbcursor[tid], cnt[tid]);
    cnt[tid] = 0;
    __syncthreads();
    for (int e = e0 + tid; e < eend; e += 256) {
        int src, dst;
        if (e < E) { src = ei[e]; dst = ei[E + e]; }
        else       { src = e - E; dst = src; }
        int b = dst / sbn;
        int off = atomicAdd(&cnt[b], 1);
        binned[gbase[b] + off] = make_int2(src, dst);
    }
}

// Pass B: one block per super-bucket; exact CSR placement into an
// exclusively-owned ~26-KB window via LDS cursors.
__global__ __launch_bounds__(512)
void place_kernel(const int* __restrict__ rowstart, const int2* __restrict__ binned,
                  int* __restrict__ sorted, int n, int sbn, int Etot) {
    __shared__ int cur[512];      // sbn <= 512
    int b = blockIdx.x;
    int dst0 = b * sbn;
    if (dst0 >= n) return;
    int rows = n - dst0; if (rows > sbn) rows = sbn;
    int tid = threadIdx.x;
    for (int i = tid; i < rows; i += 512) cur[i] = rowstart[dst0 + i];
    __syncthreads();
    int sbstart = rowstart[dst0];
    int nxt = dst0 + sbn;
    int sbend = (nxt < n) ? rowstart[nxt] : Etot;
    for (int e = sbstart + tid; e < sbend; e += 512) {
        int2 ed = binned[e];
        int pos = atomicAdd(&cur[ed.y - dst0], 1);
        sorted[pos] = ed.x;
    }
}

// ---------------------------------------------------------------------------
// K5: aggregation. One wave per dst; lane owns 2 channels; register
// accumulate, single write, atomic-free.
// ---------------------------------------------------------------------------
__global__ __launch_bounds__(256)
void agg_kernel(const int* __restrict__ rowstart, const int* __restrict__ deg,
                const int* __restrict__ sorted,
                const float* __restrict__ a_s, const float* __restrict__ a_d,
                const _Float16* __restrict__ h2, const float* __restrict__ bias,
                float* __restrict__ out, int n) {
    int dst = blockIdx.x * 4 + (threadIdx.x >> 6);
    if (dst >= n) return;
    int lane = threadIdx.x & 63;
    int head = lane >> 4;                 // channels 2*lane, 2*lane+1 share head
    int start = rowstart[dst];
    int end   = start + deg[dst];

    float ad = a_d[(size_t)dst * 4 + head];
    const unsigned* h2u = (const unsigned*)h2;
    float accx = 0.f, accy = 0.f, wsum = 0.f;

    int j = start;
    for (; j + 3 < end; j += 4) {
        int s0 = sorted[j], s1 = sorted[j + 1], s2 = sorted[j + 2], s3 = sorted[j + 3];
        float w0 = edge_w(a_s[(size_t)s0 * 4 + head] + ad);
        float w1 = edge_w(a_s[(size_t)s1 * 4 + head] + ad);
        float w2 = edge_w(a_s[(size_t)s2 * 4 + head] + ad);
        float w3 = edge_w(a_s[(size_t)s3 * 4 + head] + ad);
        float2 f0 = up2(h2u[(size_t)s0 * 64 + lane]);
        float2 f1 = up2(h2u[(size_t)s1 * 64 + lane]);
        float2 f2 = up2(h2u[(size_t)s2 * 64 + lane]);
        float2 f3 = up2(h2u[(size_t)s3 * 64 + lane]);
        accx = fmaf(w0, f0.x, accx); accy = fmaf(w0, f0.y, accy);
        accx = fmaf(w1, f1.x, accx); accy = fmaf(w1, f1.y, accy);
        accx = fmaf(w2, f2.x, accx); accy = fmaf(w2, f2.y, accy);
        accx = fmaf(w3, f3.x, accx); accy = fmaf(w3, f3.y, accy);
        wsum += (w0 + w1) + (w2 + w3);
    }
    for (; j < end; ++j) {
        int s0 = sorted[j];
        float w0 = edge_w(a_s[(size_t)s0 * 4 + head] + ad);
        float2 f0 = up2(h2u[(size_t)s0 * 64 + lane]);
        accx = fmaf(w0, f0.x, accx); accy = fmaf(w0, f0.y, accy);
        wsum += w0;
    }

    float inv = 1.f / wsum;               // deg >= 1 (self-loop) => wsum > 0
    float2 b2 = *(const float2*)&bias[lane * 2];
    *(float2*)&out[(size_t)dst * HC + lane * 2] =
        make_float2(accx * inv + b2.x, accy * inv + b2.y);
}

// ---------------------------------------------------------------------------
extern "C" void kernel_launch(void* const* d_in, const int* in_sizes, int n_in,
                              void* d_out, int out_size, void* d_ws, size_t ws_size,
                              hipStream_t stream) {
    const float* x       = (const float*)d_in[0];
    const int*   ei      = (const int*)d_in[1];
    const float* W       = (const float*)d_in[2];
    const float* att_src = (const float*)d_in[3];
    const float* att_dst = (const float*)d_in[4];
    const float* bias    = (const float*)d_in[5];

    int n = in_sizes[0] / HC;        // 100000
    int E = in_sizes[1] / 2;         // 1600000
    int Etot = E + n;
    int NB  = (n + 1023) / 1024;     // 98 scan chunks
    int sbn = (n + NSB - 1) / NSB;   // 391 nodes per super-bucket

    // workspace: h2[n*128 h] | WTh[128*128 h] | a_s[n*4 f] | a_d[n*4 f] |
    //            deg[n i] | rowstart[n i] | bsum[128 i] | sbcursor[NSB i] |
    //            binned[Etot int2] | sorted[Etot i]
    _Float16* h2     = (_Float16*)d_ws;
    _Float16* WTh    = h2 + (size_t)n * HC;
    float* a_s       = (float*)(WTh + HC * HC);
    float* a_d       = a_s + (size_t)n * HEADS;
    int*   deg       = (int*)(a_d + (size_t)n * HEADS);
    int*   rowstart  = deg + n;
    int*   bsum      = rowstart + n;
    int*   sbcursor  = bsum + 128;
    int2*  binned    = (int2*)(sbcursor + NSB);
    int*   sorted    = (int*)(binned + Etot);
    float* out       = (float*)d_out;

    wt_kernel<<<HC, HC, 0, stream>>>(W, WTh);
    gemm_mfma_kernel<<<(n + 63) / 64, 256, 0, stream>>>(x, WTh, h2, n);
    att_kernel<<<(n + 255) / 256, 256, 0, stream>>>(h2, att_src, att_dst, a_s, a_d, n);

    zero_deg_kernel<<<(n + 255) / 256, 256, 0, stream>>>(deg, n);
    hist_kernel<<<(Etot + 255) / 256, 256, 0, stream>>>(ei, E, n, deg);
    scan1_kernel<<<NB, 1024, 0, stream>>>(deg, rowstart, bsum, n);
    scan2_kernel<<<1, 128, 0, stream>>>(bsum, NB);
    scan3_kernel<<<(n + 255) / 256, 256, 0, stream>>>(rowstart, bsum, n);

    sbinit_kernel<<<1, NSB, 0, stream>>>(rowstart, sbcursor, n, sbn);
    partition_kernel<<<(Etot + 4095) / 4096, 256, 0, stream>>>(ei, E, n, sbn,
                                                               sbcursor, binned);
    place_kernel<<<NSB, 512, 0, stream>>>(rowstart, binned, sorted, n, sbn, Etot);

    agg_kernel<<<(n + 3) / 4, 256, 0, stream>>>(rowstart, deg, sorted,
                                                a_s, a_d, h2, bias, out, n);
}

// Round 6
// 284.793 us; speedup vs baseline: 7.0197x; 1.2243x over previous
//
#include <hip/hip_runtime.h>
#include <cstddef>

#define HEADS 4
#define HC 128          // HEADS * C
#define SLOPE 0.2f
#define NSB 512         // super-buckets (fixed-stride regions)
#define SBCAP 4096      // slots per super-bucket (expected fill ~3330, >13 sigma)

using half8 = __attribute__((ext_vector_type(8))) _Float16;
using f32x4 = __attribute__((ext_vector_type(4))) float;

__device__ __forceinline__ float edge_w(float v) {
    v = v > 0.f ? v : SLOPE * v;              // leaky relu
    return __expf(v);                         // |logit| small; no max-sub needed
}
__device__ __forceinline__ float2 up2(unsigned w) {   // unpack 2 fp16
    union { unsigned u; _Float16 f[2]; } c; c.u = w;
    return make_float2((float)c.f[0], (float)c.f[1]);
}

// ---------------------------------------------------------------------------
// K0: WTh[n][k] = fp16(W[k][n])  (transpose + cast, 128x128)
// ---------------------------------------------------------------------------
__global__ void wt_kernel(const float* __restrict__ W, _Float16* __restrict__ WTh) {
    int k = threadIdx.x;          // 0..127
    int nn = blockIdx.x;          // 0..127
    WTh[nn * HC + k] = (_Float16)W[k * HC + nn];
}

// ---------------------------------------------------------------------------
// K1: h2 = fp16(x @ W) via MFMA 16x16x32 f16, with fused attention-logit
// epilogue: a_s[row][h] = <h[row,h,:], att_src[h,:]> reduced via shfl_xor
// over the 16 t-lanes (C/D layout: col = ct*16 + t, head = ct>>1).
// ---------------------------------------------------------------------------
__global__ __launch_bounds__(256)
void gemm_att_kernel(const float* __restrict__ x, const _Float16* __restrict__ WTh,
                     const float* __restrict__ att_src, const float* __restrict__ att_dst,
                     _Float16* __restrict__ h2,
                     float* __restrict__ a_s, float* __restrict__ a_d, int n) {
    int tid  = threadIdx.x;
    int wv   = tid >> 6;
    int lane = tid & 63;
    int t    = lane & 15;     // A row / D col within tile
    int q    = lane >> 4;     // quad
    int r0   = blockIdx.x * 64 + wv * 16;

    f32x4 acc[8];
#pragma unroll
    for (int ct = 0; ct < 8; ++ct) acc[ct] = (f32x4){0.f, 0.f, 0.f, 0.f};

    int  arow = r0 + t;
    bool aval = arow < n;
    const float* xp = x + (size_t)(aval ? arow : 0) * HC;

    for (int kc = 0; kc < 4; ++kc) {
        int k0 = kc * 32 + q * 8;
        half8 a;
        float4 fa = *(const float4*)(xp + k0);
        float4 fb = *(const float4*)(xp + k0 + 4);
        if (!aval) { fa = make_float4(0.f,0.f,0.f,0.f); fb = fa; }
        a[0] = (_Float16)fa.x; a[1] = (_Float16)fa.y;
        a[2] = (_Float16)fa.z; a[3] = (_Float16)fa.w;
        a[4] = (_Float16)fb.x; a[5] = (_Float16)fb.y;
        a[6] = (_Float16)fb.z; a[7] = (_Float16)fb.w;
#pragma unroll
        for (int ct = 0; ct < 8; ++ct) {
            half8 b = *(const half8*)(WTh + (size_t)(ct * 16 + t) * HC + k0);
            acc[ct] = __builtin_amdgcn_mfma_f32_16x16x32_f16(a, b, acc[ct], 0, 0, 0);
        }
    }

    // store h2 (fp16)
#pragma unroll
    for (int reg = 0; reg < 4; ++reg) {
        int row = r0 + q * 4 + reg;
        if (row < n) {
#pragma unroll
            for (int ct = 0; ct < 8; ++ct)
                h2[(size_t)row * HC + ct * 16 + t] = (_Float16)acc[ct][reg];
        }
    }

    // fused attention logits: per-lane att values at channel ct*16+t
    float asv[8], adv[8];
#pragma unroll
    for (int ct = 0; ct < 8; ++ct) {
        asv[ct] = att_src[ct * 16 + t];
        adv[ct] = att_dst[ct * 16 + t];
    }
#pragma unroll
    for (int reg = 0; reg < 4; ++reg) {
        int row = r0 + q * 4 + reg;
        float4 ps, pd;
        ps.x = acc[0][reg]*asv[0] + acc[1][reg]*asv[1];
        ps.y = acc[2][reg]*asv[2] + acc[3][reg]*asv[3];
        ps.z = acc[4][reg]*asv[4] + acc[5][reg]*asv[5];
        ps.w = acc[6][reg]*asv[6] + acc[7][reg]*asv[7];
        pd.x = acc[0][reg]*adv[0] + acc[1][reg]*adv[1];
        pd.y = acc[2][reg]*adv[2] + acc[3][reg]*adv[3];
        pd.z = acc[4][reg]*adv[4] + acc[5][reg]*adv[5];
        pd.w = acc[6][reg]*adv[6] + acc[7][reg]*adv[7];
#pragma unroll
        for (int m = 1; m < 16; m <<= 1) {
            ps.x += __shfl_xor(ps.x, m); ps.y += __shfl_xor(ps.y, m);
            ps.z += __shfl_xor(ps.z, m); ps.w += __shfl_xor(ps.w, m);
            pd.x += __shfl_xor(pd.x, m); pd.y += __shfl_xor(pd.y, m);
            pd.z += __shfl_xor(pd.z, m); pd.w += __shfl_xor(pd.w, m);
        }
        if (t == 0 && row < n) {
            ((float4*)a_s)[row] = ps;
            ((float4*)a_d)[row] = pd;
        }
    }
}

// ---------------------------------------------------------------------------
// sbinit: fixed-stride bucket cursors
// ---------------------------------------------------------------------------
__global__ void sbinit_kernel(int* __restrict__ sbcursor) {
    sbcursor[threadIdx.x] = threadIdx.x * SBCAP;
}

// ---------------------------------------------------------------------------
// partition: each block owns a 4096-edge chunk; LDS per-bucket counts; ONE
// global atomic per block x bucket reserves a block-private run; int2
// (src,dst) written into block-owned runs (<=2 blocks per 64-B line).
// ---------------------------------------------------------------------------
__global__ __launch_bounds__(256)
void partition_kernel(const int* __restrict__ ei, int E, int n, int sbn,
                      int* __restrict__ sbcursor, int2* __restrict__ binned) {
    __shared__ int cnt[NSB];
    __shared__ int gbase[NSB];
    int tid = threadIdx.x;
    int Etot = E + n;
    int e0 = blockIdx.x * 4096;
    int eend = e0 + 4096; if (eend > Etot) eend = Etot;

    cnt[tid] = 0; cnt[tid + 256] = 0;
    __syncthreads();
    for (int e = e0 + tid; e < eend; e += 256) {
        int dst = (e < E) ? ei[E + e] : (e - E);
        atomicAdd(&cnt[dst / sbn], 1);
    }
    __syncthreads();
    gbase[tid]       = atomicAdd(&sbcursor[tid],       cnt[tid]);
    gbase[tid + 256] = atomicAdd(&sbcursor[tid + 256], cnt[tid + 256]);
    cnt[tid] = 0; cnt[tid + 256] = 0;
    __syncthreads();
    for (int e = e0 + tid; e < eend; e += 256) {
        int src, dst;
        if (e < E) { src = ei[e]; dst = ei[E + e]; }
        else       { src = e - E; dst = src; }
        int b = dst / sbn;
        int off = atomicAdd(&cnt[b], 1);
        binned[gbase[b] + off] = make_int2(src, dst);
    }
}

// ---------------------------------------------------------------------------
// place: one block per super-bucket. LDS degree count + LDS exclusive scan
// gives bucket-local CSR; writes absolute rowstart/deg and exact-placed
// sorted[] into the bucket's exclusively-owned window (single XCD).
// ---------------------------------------------------------------------------
__global__ __launch_bounds__(256)
void place_kernel(const int* __restrict__ sbcursor, const int2* __restrict__ binned,
                  int* __restrict__ sorted, int* __restrict__ rowstart,
                  int* __restrict__ deg, int n, int sbn) {
    __shared__ int cnt[256];      // sbn <= 256
    __shared__ int pos[256];
    int b = blockIdx.x;
    int dst0 = b * sbn;
    if (dst0 >= n) return;
    int rows = n - dst0; if (rows > sbn) rows = sbn;
    int tid = threadIdx.x;

    cnt[tid] = 0;
    __syncthreads();
    int wstart = b * SBCAP;
    int wend   = sbcursor[b];
    for (int e = wstart + tid; e < wend; e += 256)
        atomicAdd(&cnt[binned[e].y - dst0], 1);
    __syncthreads();

    int d = cnt[tid];
    pos[tid] = d;
    __syncthreads();
#pragma unroll
    for (int off = 1; off < 256; off <<= 1) {
        int v = (tid >= off) ? pos[tid - off] : 0;
        __syncthreads();
        pos[tid] += v;
        __syncthreads();
    }
    int excl = pos[tid] - d;
    if (tid < rows) {
        rowstart[dst0 + tid] = wstart + excl;
        deg[dst0 + tid] = d;
    }
    cnt[tid] = excl;              // reuse as placement cursor
    __syncthreads();
    for (int e = wstart + tid; e < wend; e += 256) {
        int2 ed = binned[e];
        int p = atomicAdd(&cnt[ed.y - dst0], 1);
        sorted[wstart + p] = ed.x;
    }
}

// ---------------------------------------------------------------------------
// agg: one wave per dst. Quarter-wave per edge: lane owns 8 channels via one
// uint4 load, so one load instruction covers 4 edges' full rows; unroll x2
// -> 8 edges in flight. Cross-sub shfl reduce; single coalesced write.
// ---------------------------------------------------------------------------
__global__ __launch_bounds__(256)
void agg_kernel(const int* __restrict__ rowstart, const int* __restrict__ deg,
                const int* __restrict__ sorted,
                const float* __restrict__ a_s, const float* __restrict__ a_d,
                const _Float16* __restrict__ h2, const float* __restrict__ bias,
                float* __restrict__ out, int n) {
    int dst = blockIdx.x * 4 + (threadIdx.x >> 6);
    if (dst >= n) return;
    int lane = threadIdx.x & 63;
    int li   = lane & 15;          // channel group: ch = li*8 .. li*8+7
    int sub  = lane >> 4;          // edge slot within group of 4
    int head = li >> 2;            // ch0 = li*8 -> head = li*8/32
    int start = rowstart[dst];
    int cntv  = deg[dst];          // >= 1 (self-loop)

    float ad = a_d[(size_t)dst * 4 + head];
    const uint4* h4 = (const uint4*)h2;    // row = 16 uint4
    float acc[8] = {0.f,0.f,0.f,0.f,0.f,0.f,0.f,0.f};
    float wsum = 0.f;

    for (int j = 0; j < cntv; j += 8) {
#pragma unroll
        for (int k = 0; k < 2; ++k) {
            int idx = j + k * 4 + sub;
            bool valid = idx < cntv;
            int s = sorted[start + (valid ? idx : cntv - 1)];
            float w = valid ? edge_w(a_s[(size_t)s * 4 + head] + ad) : 0.f;
            uint4 hv = h4[(size_t)s * 16 + li];
            float2 f0 = up2(hv.x), f1 = up2(hv.y), f2 = up2(hv.z), f3 = up2(hv.w);
            acc[0] = fmaf(w, f0.x, acc[0]); acc[1] = fmaf(w, f0.y, acc[1]);
            acc[2] = fmaf(w, f1.x, acc[2]); acc[3] = fmaf(w, f1.y, acc[3]);
            acc[4] = fmaf(w, f2.x, acc[4]); acc[5] = fmaf(w, f2.y, acc[5]);
            acc[6] = fmaf(w, f3.x, acc[6]); acc[7] = fmaf(w, f3.y, acc[7]);
            wsum += w;
        }
    }

    // reduce across the 4 edge slots (lanes differ in bits 4,5)
#pragma unroll
    for (int k = 0; k < 8; ++k) {
        acc[k] += __shfl_xor(acc[k], 16);
        acc[k] += __shfl_xor(acc[k], 32);
    }
    wsum += __shfl_xor(wsum, 16);
    wsum += __shfl_xor(wsum, 32);

    if (sub == 0) {
        float inv = 1.f / wsum;
        float4 b0 = ((const float4*)bias)[li * 2];
        float4 b1 = ((const float4*)bias)[li * 2 + 1];
        float4 o0 = make_float4(acc[0]*inv + b0.x, acc[1]*inv + b0.y,
                                acc[2]*inv + b0.z, acc[3]*inv + b0.w);
        float4 o1 = make_float4(acc[4]*inv + b1.x, acc[5]*inv + b1.y,
                                acc[6]*inv + b1.z, acc[7]*inv + b1.w);
        float4* op = (float4*)(out + (size_t)dst * HC);
        op[li * 2]     = o0;
        op[li * 2 + 1] = o1;
    }
}

// ---------------------------------------------------------------------------
extern "C" void kernel_launch(void* const* d_in, const int* in_sizes, int n_in,
                              void* d_out, int out_size, void* d_ws, size_t ws_size,
                              hipStream_t stream) {
    const float* x       = (const float*)d_in[0];
    const int*   ei      = (const int*)d_in[1];
    const float* W       = (const float*)d_in[2];
    const float* att_src = (const float*)d_in[3];
    const float* att_dst = (const float*)d_in[4];
    const float* bias    = (const float*)d_in[5];

    int n = in_sizes[0] / HC;        // 100000
    int E = in_sizes[1] / 2;         // 1600000
    int Etot = E + n;
    int sbn = (n + NSB - 1) / NSB;   // 196 nodes per super-bucket (<=256)

    // workspace: h2[n*128 h] | WTh[128*128 h] | a_s[n*4 f] | a_d[n*4 f] |
    //            rowstart[n i] | deg[n i] | sbcursor[NSB i] |
    //            binned[NSB*SBCAP int2] | sorted[NSB*SBCAP i]
    _Float16* h2     = (_Float16*)d_ws;
    _Float16* WTh    = h2 + (size_t)n * HC;
    float* a_s       = (float*)(WTh + HC * HC);
    float* a_d       = a_s + (size_t)n * HEADS;
    int*   rowstart  = (int*)(a_d + (size_t)n * HEADS);
    int*   deg       = rowstart + n;
    int*   sbcursor  = deg + n;
    int2*  binned    = (int2*)(sbcursor + NSB);
    int*   sorted    = (int*)(binned + (size_t)NSB * SBCAP);
    float* out       = (float*)d_out;

    wt_kernel<<<HC, HC, 0, stream>>>(W, WTh);
    gemm_att_kernel<<<(n + 63) / 64, 256, 0, stream>>>(x, WTh, att_src, att_dst,
                                                       h2, a_s, a_d, n);
    sbinit_kernel<<<1, NSB, 0, stream>>>(sbcursor);
    partition_kernel<<<(Etot + 4095) / 4096, 256, 0, stream>>>(ei, E, n, sbn,
                                                               sbcursor, binned);
    place_kernel<<<NSB, 256, 0, stream>>>(sbcursor, binned, sorted,
                                          rowstart, deg, n, sbn);
    agg_kernel<<<(n + 3) / 4, 256, 0, stream>>>(rowstart, deg, sorted,
                                                a_s, a_d, h2, bias, out, n);
}